// Round 13
// baseline (93.827 us; speedup 1.0000x reference)
//
#include <hip/hip_runtime.h>

typedef _Float16 half8 __attribute__((ext_vector_type(8)));
typedef __fp16 fp16x2 __attribute__((ext_vector_type(2)));
typedef float f32x4 __attribute__((ext_vector_type(4)));
typedef float f32x16 __attribute__((ext_vector_type(16)));
typedef unsigned int u32;
typedef unsigned short u16;

#define NB 4
#define NC 128
#define NN 4096
#define THR 8.0f

__device__ __forceinline__ void gload16(const void* g, void* l) {
    __builtin_amdgcn_global_load_lds(
        (const __attribute__((address_space(1))) u32*)g,
        (__attribute__((address_space(3))) u32*)l, 16, 0, 0);
}
__device__ __forceinline__ float h2f_u(u32 u) {
    u16 us = (u16)u;
    _Float16 h;
    __builtin_memcpy(&h, &us, 2);
    return (float)h;
}
__device__ __forceinline__ u16 f2h_u(float f) {
    _Float16 h = (_Float16)f;
    u16 us;
    __builtin_memcpy(&us, &h, 2);
    return us;
}
__device__ __forceinline__ float exp2_fast(float x) {
#if __has_builtin(__builtin_amdgcn_exp2f)
    return __builtin_amdgcn_exp2f(x);
#else
    return exp2f(x);
#endif
}
__device__ __forceinline__ int xs_addr(int c, int n) {
    return ((c << 8) + (n << 2)) ^ (((c >> 3) & 1) << 6);
}

// ---------------------------------------------------------------------------
// Kernel 1: QKV projection via fp16 MFMA (unchanged from R12; works).
// ---------------------------------------------------------------------------
__global__ __launch_bounds__(512, 2) void qkv_proj_kernel(
    const float* __restrict__ x,
    const float* __restrict__ wq, const float* __restrict__ bq,
    const float* __restrict__ wk, const float* __restrict__ bk,
    const float* __restrict__ wv, const float* __restrict__ bv,
    _Float16* __restrict__ Qb, _Float16* __restrict__ Kb, _Float16* __restrict__ Vt)
{
    const int tid  = threadIdx.x;
    const int b    = blockIdx.x >> 6;
    const int n0   = (blockIdx.x & 63) << 6;
    const int lane = tid & 63;
    const int wave = __builtin_amdgcn_readfirstlane(tid >> 6);
    const int l15  = lane & 15, lg = lane >> 4;
    const int obase = wave * 16;

    __shared__ __align__(16) unsigned char xsm[32768];

    #pragma unroll
    for (int kk = 0; kk < 4; ++kk) {
        int g = kk * 512 + tid;
        int c = g >> 4, n4 = (g & 15) << 2;
        *(float4*)(xsm + xs_addr(c, n4)) = *(const float4*)(x + (size_t)(b * NC + c) * NN + n0 + n4);
    }
    __syncthreads();

    half8 bx[4][4];
    #pragma unroll
    for (int ct2 = 0; ct2 < 4; ++ct2) {
        int n = ct2 * 16 + l15;
        #pragma unroll
        for (int kc = 0; kc < 4; ++kc) {
            half8 h;
            #pragma unroll
            for (int j = 0; j < 8; ++j) {
                int c = kc * 32 + lg * 8 + j;
                h[j] = (_Float16)(*(const float*)(xsm + xs_addr(c, n)));
            }
            bx[ct2][kc] = h;
        }
    }
    __syncthreads();                       // xsm free for output bounce

    #pragma unroll 1
    for (int mat = 0; mat < 3; ++mat) {
        const float* __restrict__ W  = (mat == 0) ? wq : ((mat == 1) ? wk : wv);
        const float* __restrict__ bi = (mat == 0) ? bq : ((mat == 1) ? bk : bv);

        half8 aw[4];
        #pragma unroll
        for (int kc = 0; kc < 4; ++kc) {
            const float* wp = W + (size_t)(obase + l15) * NC + kc * 32 + lg * 8;
            float4 w0 = *(const float4*)(wp);
            float4 w1 = *(const float4*)(wp + 4);
            half8 h;
            h[0] = (_Float16)w0.x; h[1] = (_Float16)w0.y; h[2] = (_Float16)w0.z; h[3] = (_Float16)w0.w;
            h[4] = (_Float16)w1.x; h[5] = (_Float16)w1.y; h[6] = (_Float16)w1.z; h[7] = (_Float16)w1.w;
            aw[kc] = h;
        }
        float bvv[4];
        #pragma unroll
        for (int r = 0; r < 4; ++r) bvv[r] = bi[obase + lg * 4 + r];

        f32x4 acc[4];
        #pragma unroll
        for (int ct2 = 0; ct2 < 4; ++ct2) acc[ct2] = (f32x4){0.f, 0.f, 0.f, 0.f};
        #pragma unroll
        for (int kc = 0; kc < 4; ++kc) {
            #pragma unroll
            for (int ct2 = 0; ct2 < 4; ++ct2)
                acc[ct2] = __builtin_amdgcn_mfma_f32_16x16x32_f16(aw[kc], bx[ct2][kc], acc[ct2], 0, 0, 0);
        }

        if (mat < 2) {
            _Float16* dst = (mat == 0) ? Qb : Kb;
            const int cslot = wave * 2 + (lg >> 1);
            const int half8off = (lg & 1) * 8;
            #pragma unroll
            for (int ct2 = 0; ct2 < 4; ++ct2) {
                int nl = ct2 * 16 + l15;
                u16 pk[4];
                #pragma unroll
                for (int r = 0; r < 4; ++r) pk[r] = f2h_u(acc[ct2][r] + bvv[r]);
                unsigned long long v;
                __builtin_memcpy(&v, pk, 8);
                *(unsigned long long*)(xsm + nl * 256 + (((cslot ^ (nl & 15)) << 4) | half8off)) = v;
            }
            __syncthreads();
            {
                const int nl = tid >> 3;
                const int s2 = (tid & 7) << 1;
                uint4 v0 = *(const uint4*)(xsm + nl * 256 + ((s2 ^ (nl & 15)) << 4));
                uint4 v1 = *(const uint4*)(xsm + nl * 256 + (((s2 + 1) ^ (nl & 15)) << 4));
                _Float16* dp = dst + (size_t)(b * NN + n0 + nl) * NC + s2 * 8;
                *(uint4*)(dp)     = v0;
                *(uint4*)(dp + 8) = v1;
            }
            __syncthreads();
        } else {
            #pragma unroll
            for (int ct2 = 0; ct2 < 4; ++ct2) {
                int n = n0 + ct2 * 16 + l15;
                #pragma unroll
                for (int r = 0; r < 4; ++r)
                    Vt[(size_t)(b * NC + obase + lg * 4 + r) * NN + n] = (_Float16)(acc[ct2][r] + bvv[r]);
            }
        }
    }
}

// ---------------------------------------------------------------------------
// Kernel 2: flash attention with CROSS-TILE MFMA/VALU OVERLAP.
// Per step: issue QK(it+1) MFMAs (into next score regs), then softmax(it) on
// VALU (overlaps in-flight MFMAs), then PV(it). K triple-buffered (3x16KB),
// V double-buffered (2x16KB) = 80KB LDS -> 2 blocks/CU exactly. Counted
// vmcnt(8/4/0) keeps stages in flight. S=4, 32x32x16, 32 q/wave.
// ---------------------------------------------------------------------------
__global__ __launch_bounds__(256, 1) void attn_kernel(
    const _Float16* __restrict__ Qb, const _Float16* __restrict__ Kb,
    const _Float16* __restrict__ Vt, float* __restrict__ out,
    u16* __restrict__ parts, float* __restrict__ statM, float* __restrict__ statL,
    int lg2S)
{
    const int S = 1 << lg2S;
    const int tid = threadIdx.x;
    const int cpx = gridDim.x >> 3;
    const int lin = (blockIdx.x & 7) * cpx + (blockIdx.x >> 3);
    const int qt   = lin & 31;             // 32 q-tiles of 128
    const int rest = lin >> 5;             // = b * S + sp
    const int sp = rest & (S - 1);
    const int b  = rest >> lg2S;

    const int n0    = qt << 7;             // 128 q per block
    const int kvlen = NN >> lg2S;
    const int kv0   = sp * kvlen;
    const int iters = kvlen >> 6;          // 16 (S=4) or 64 (S=1): always even

    const int lane = tid & 63;
    const int wave = __builtin_amdgcn_readfirstlane(tid >> 6);
    const int l31 = lane & 31, hi = lane >> 5;
    const int s7 = l31 & 7;
    const int s15 = l31 & 15;

    // K slots: 0,16K,32K ; V slots: 48K,64K. Total 80KB.
    __shared__ __align__(16) unsigned char smem[81920];

    int kgo[4], vgo[4], klds[4];
    #pragma unroll
    for (int j = 0; j < 4; ++j) {
        int i = (wave * 4 + j) * 64 + lane;          // chunk 0..1023 (16B units)
        int lam = i >> 4, slot = i & 15;
        int cc = slot ^ (lam & 15);                  // 4-bit XOR swizzle
        int kv = (lam & 51) | ((lam & 4) << 1) | ((lam & 8) >> 1);  // swap bits 2,3
        kgo[j] = kv * NC + cc * 8;
        int c = i >> 3, s2 = i & 7;
        vgo[j] = c * NN + ((s2 ^ (c & 7)) << 3);
        klds[j] = (wave * 4 + j) * 1024;
    }
    const _Float16* Kt0 = Kb + ((size_t)b * NN + kv0) * NC;
    const _Float16* Vt0 = Vt + (size_t)b * NC * NN + kv0;

    int koff[8];
    #pragma unroll
    for (int kc = 0; kc < 8; ++kc) {
        int cc = kc * 2 + hi;
        koff[kc] = l31 * 256 + ((cc ^ s15) << 4);
    }
    int voff[4];
    #pragma unroll
    for (int ks = 0; ks < 4; ++ks) {
        int cc2 = ks * 2 + hi;
        voff[ks] = l31 * 128 + ((cc2 ^ s7) << 4);
    }

#define STAGEK(T, LB)                                                        \
    do { const _Float16* Kp_ = Kt0 + (size_t)(T) * 64 * NC;                  \
         _Pragma("unroll")                                                   \
         for (int j = 0; j < 4; ++j) gload16(Kp_ + kgo[j], smem + (LB) + klds[j]); } while (0)
#define STAGEV(T, LB)                                                        \
    do { const _Float16* Vp_ = Vt0 + (T) * 64;                               \
         _Pragma("unroll")                                                   \
         for (int j = 0; j < 4; ++j) gload16(Vp_ + vgo[j], smem + (LB) + klds[j]); } while (0)

    // ---- prologue: Q frags, then K0,K1,V0 (needed first) and K2,V1 (in flight)
    half8 aq[8];
    {
        const _Float16* qp = Qb + (size_t)(b * NN + n0 + wave * 32 + l31) * NC + hi * 8;
        #pragma unroll
        for (int kc = 0; kc < 8; ++kc) aq[kc] = *(const half8*)(qp + kc * 16);
    }
    STAGEK(0, 0);
    STAGEK(1, 16384);
    STAGEV(0, 49152);
    STAGEK(2, 32768);
    STAGEV(1, 65536);
    asm volatile("s_waitcnt vmcnt(8)" ::: "memory");   // Q,K0,K1,V0 landed
    __builtin_amdgcn_s_barrier();

    float mrun = -3.0e38f, lsum = 0.f;
    f32x16 o[4];
    #pragma unroll
    for (int ct = 0; ct < 4; ++ct)
        #pragma unroll
        for (int r = 0; r < 16; ++r) o[ct][r] = 0.f;

    const float L2E = 1.44269504f;

    f32x16 sA0, sA1, sB0, sB1;
    // QK(0) from K slot 0
    #pragma unroll
    for (int r = 0; r < 16; ++r) { sA0[r] = 0.f; sA1[r] = 0.f; }
    #pragma unroll
    for (int kc = 0; kc < 8; ++kc) {
        half8 k0 = *(const half8*)(smem + koff[kc]);
        half8 k1 = *(const half8*)(smem + koff[kc] + 8192);
        sA0 = __builtin_amdgcn_mfma_f32_32x32x16_f16(k0, aq[kc], sA0, 0, 0, 0);
        sA1 = __builtin_amdgcn_mfma_f32_32x32x16_f16(k1, aq[kc], sA1, 0, 0, 0);
    }

    int kslNext = 1;    // LDS K-slot of tile it+1
    int kslStage = 0;   // LDS K-slot for staging tile it+3
    int vcur = 0;       // LDS V-slot of tile it

#define STEP(C0, C1, N0, N1, IT)                                                  \
    do {                                                                          \
        const int it_ = (IT);                                                     \
        if (it_ + 1 < iters) {            /* QK(it+1) -> N (overlaps softmax) */  \
            const int kb_ = kslNext << 14;                                        \
            __builtin_amdgcn_s_setprio(1);                                        \
            _Pragma("unroll")                                                     \
            for (int r = 0; r < 16; ++r) { N0[r] = 0.f; N1[r] = 0.f; }            \
            _Pragma("unroll")                                                     \
            for (int kc = 0; kc < 8; ++kc) {                                      \
                half8 k0_ = *(const half8*)(smem + kb_ + koff[kc]);               \
                half8 k1_ = *(const half8*)(smem + kb_ + koff[kc] + 8192);        \
                N0 = __builtin_amdgcn_mfma_f32_32x32x16_f16(k0_, aq[kc], N0, 0, 0, 0); \
                N1 = __builtin_amdgcn_mfma_f32_32x32x16_f16(k1_, aq[kc], N1, 0, 0, 0); \
            }                                                                     \
            __builtin_amdgcn_s_setprio(0);                                        \
            kslNext = (kslNext == 2) ? 0 : kslNext + 1;                           \
        }                                                                         \
        /* ---- softmax(it) on C0/C1 (VALU; overlaps the MFMAs above) ---- */     \
        {                                                                         \
            float tm = fmaxf(C0[0], C0[1]);                                       \
            _Pragma("unroll")                                                     \
            for (int r = 2; r < 16; r += 2) tm = fmaxf(tm, fmaxf(C0[r], C0[r + 1])); \
            _Pragma("unroll")                                                     \
            for (int r = 0; r < 16; r += 2) tm = fmaxf(tm, fmaxf(C1[r], C1[r + 1])); \
            tm = fmaxf(tm, __shfl_xor(tm, 32, 64));                               \
            if (__any(tm > mrun + THR)) {                                         \
                float mnew = fmaxf(mrun, tm);                                     \
                float sc = __expf(mrun - mnew);                                   \
                _Pragma("unroll")                                                 \
                for (int ct = 0; ct < 4; ++ct)                                    \
                    _Pragma("unroll")                                             \
                    for (int r = 0; r < 16; ++r) o[ct][r] *= sc;                  \
                lsum *= sc;                                                       \
                mrun = mnew;                                                      \
            }                                                                     \
            float nm = -mrun * L2E;                                               \
            float psum = 0.f;                                                     \
            _Pragma("unroll")                                                     \
            for (int r = 0; r < 16; ++r) {                                        \
                C0[r] = exp2_fast(fmaf(C0[r], L2E, nm));                          \
                C1[r] = exp2_fast(fmaf(C1[r], L2E, nm));                          \
                psum += C0[r] + C1[r];                                            \
            }                                                                     \
            psum += __shfl_xor(psum, 32, 64);                                     \
            lsum += psum;                                                         \
        }                                                                         \
        /* ---- P -> A-frags ---- */                                              \
        union H8_ { fp16x2 h2[4]; half8 h8; };                                    \
        half8 pa[4];                                                              \
        {                                                                         \
            H8_ u0, u1, u2, u3;                                                   \
            _Pragma("unroll")                                                     \
            for (int t = 0; t < 4; ++t) {                                         \
                u0.h2[t] = __builtin_amdgcn_cvt_pkrtz(C0[2 * t],     C0[2 * t + 1]); \
                u1.h2[t] = __builtin_amdgcn_cvt_pkrtz(C0[8 + 2 * t], C0[9 + 2 * t]); \
                u2.h2[t] = __builtin_amdgcn_cvt_pkrtz(C1[2 * t],     C1[2 * t + 1]); \
                u3.h2[t] = __builtin_amdgcn_cvt_pkrtz(C1[8 + 2 * t], C1[9 + 2 * t]); \
            }                                                                     \
            pa[0] = u0.h8; pa[1] = u1.h8; pa[2] = u2.h8; pa[3] = u3.h8;           \
        }                                                                         \
        /* ---- O += V^T P from V slot vcur ---- */                               \
        {                                                                         \
            const int vb_ = 49152 + (vcur << 14);                                 \
            __builtin_amdgcn_s_setprio(1);                                        \
            _Pragma("unroll")                                                     \
            for (int ks = 0; ks < 4; ++ks) {                                      \
                _Pragma("unroll")                                                 \
                for (int ct = 0; ct < 4; ++ct) {                                  \
                    half8 vf_ = *(const half8*)(smem + vb_ + voff[ks] + ct * 4096); \
                    o[ct] = __builtin_amdgcn_mfma_f32_32x32x16_f16(vf_, pa[ks], o[ct], 0, 0, 0); \
                }                                                                 \
            }                                                                     \
            __builtin_amdgcn_s_setprio(0);                                       \
        }                                                                         \
        /* ---- stage ahead: K(it+3) -> kslStage, V(it+2) -> vcur slot ---- */    \
        if (it_ + 1 < iters) {                                                    \
            asm volatile("" ::: "memory");                                        \
            __builtin_amdgcn_s_barrier();                                         \
            const bool k3_ = (it_ + 3 < iters), v2_ = (it_ + 2 < iters);          \
            if (k3_) { STAGEK(it_ + 3, kslStage << 14);                           \
                       kslStage = (kslStage == 2) ? 0 : kslStage + 1; }           \
            if (v2_) { STAGEV(it_ + 2, 49152 + (vcur << 14)); }                   \
            if (k3_)      asm volatile("s_waitcnt vmcnt(8)" ::: "memory");        \
            else if (v2_) asm volatile("s_waitcnt vmcnt(4)" ::: "memory");        \
            else          asm volatile("s_waitcnt vmcnt(0)" ::: "memory");        \
            asm volatile("" ::: "memory");                                        \
            __builtin_amdgcn_s_barrier();                                         \
        }                                                                         \
        vcur ^= 1;                                                                \
    } while (0)

    for (int it = 0; it < iters; it += 2) {
        STEP(sA0, sA1, sB0, sB1, it);
        STEP(sB0, sB1, sA0, sA1, it + 1);
    }
#undef STEP
#undef STAGEK
#undef STAGEV

    // ---- epilogue (all q-column-local); partials normalized per split ----
    const int nq = n0 + wave * 32 + l31;
    const int rbase = 4 * hi;
    float inv = 1.0f / lsum;
    if (lg2S == 0) {
        #pragma unroll
        for (int ct = 0; ct < 4; ++ct)
            #pragma unroll
            for (int rg = 0; rg < 16; ++rg) {
                int c = ct * 32 + (rg & 3) + ((rg >> 2) << 3) + rbase;
                out[(size_t)(b * NC + c) * NN + nq] = o[ct][rg] * inv;
            }
    } else {
        if (hi == 0) {
            statM[(sp * NB + b) * NN + nq] = mrun;
            statL[(sp * NB + b) * NN + nq] = lsum;
        }
        const size_t pbase = (size_t)sp * ((size_t)NB * NC * NN) + (size_t)b * NC * NN + nq;
        #pragma unroll
        for (int ct = 0; ct < 4; ++ct)
            #pragma unroll
            for (int rg = 0; rg < 16; ++rg) {
                int c = ct * 32 + (rg & 3) + ((rg >> 2) << 3) + rbase;
                parts[pbase + (size_t)c * NN] = f2h_u(o[ct][rg] * inv);
            }
    }
}

// ---------------------------------------------------------------------------
// Kernel 3: merge 4 normalized partials. grid NB*64, block 256.
// ---------------------------------------------------------------------------
__global__ __launch_bounds__(256) void merge_kernel(
    const u16* __restrict__ parts,
    const float* __restrict__ statM, const float* __restrict__ statL,
    float* __restrict__ out)
{
    const int b  = blockIdx.x >> 6;
    const int nb = (blockIdx.x & 63) << 6;
    const int t  = threadIdx.x;
    const int n  = nb + ((t & 31) << 1);
    const int cg = t >> 5;
    const size_t PST = (size_t)NB * NC * NN;

    float w0[4], w1[4];
    {
        float M0 = -3.0e38f, M1 = -3.0e38f;
        #pragma unroll
        for (int sp = 0; sp < 4; ++sp) {
            w0[sp] = statM[(sp * NB + b) * NN + n];
            w1[sp] = statM[(sp * NB + b) * NN + n + 1];
            M0 = fmaxf(M0, w0[sp]); M1 = fmaxf(M1, w1[sp]);
        }
        float d0 = 0.f, d1 = 0.f;
        #pragma unroll
        for (int sp = 0; sp < 4; ++sp) {
            float e0 = __expf(w0[sp] - M0) * statL[(sp * NB + b) * NN + n];
            float e1 = __expf(w1[sp] - M1) * statL[(sp * NB + b) * NN + n + 1];
            w0[sp] = e0; w1[sp] = e1; d0 += e0; d1 += e1;
        }
        d0 = 1.f / d0; d1 = 1.f / d1;
        #pragma unroll
        for (int sp = 0; sp < 4; ++sp) { w0[sp] *= d0; w1[sp] *= d1; }
    }

    #pragma unroll 4
    for (int i = 0; i < 16; ++i) {
        int c = cg * 16 + i;
        size_t e = (size_t)(b * NC + c) * NN + n;
        float a0 = 0.f, a1 = 0.f;
        #pragma unroll
        for (int sp = 0; sp < 4; ++sp) {
            u32 v = *(const u32*)(parts + sp * PST + e);
            a0 += w0[sp] * h2f_u(v);
            a1 += w1[sp] * h2f_u(v >> 16);
        }
        float2 r; r.x = a0; r.y = a1;
        *(float2*)(out + e) = r;
    }
}

extern "C" void kernel_launch(void* const* d_in, const int* in_sizes, int n_in,
                              void* d_out, int out_size, void* d_ws, size_t ws_size,
                              hipStream_t stream)
{
    const float* x  = (const float*)d_in[0];
    const float* wq = (const float*)d_in[1];
    const float* bq = (const float*)d_in[2];
    const float* wk = (const float*)d_in[3];
    const float* bk = (const float*)d_in[4];
    const float* wv = (const float*)d_in[5];
    const float* bv = (const float*)d_in[6];

    const size_t TE = (size_t)NB * NN * NC;              // 2M elems / tensor
    _Float16* Qb = (_Float16*)d_ws;
    _Float16* Kb = Qb + TE;
    _Float16* Vb = Kb + TE;
    char* base = (char*)d_ws;
    const size_t statOff = 3 * TE * 2;                   // 12 MB
    const size_t statSz  = (size_t)4 * NB * NN * 4;      // 256 KB (S=4)
    float* statM = (float*)(base + statOff);
    float* statL = (float*)(base + statOff + statSz);
    const size_t pOff = statOff + 2 * statSz;
    u16* parts = (u16*)(base + pOff);
    const size_t need = pOff + 4 * TE * 2;               // + 16 MB partials

    int lg2S = (ws_size >= need) ? 2 : 0;                // S=4 or fallback S=1

    qkv_proj_kernel<<<dim3(256), dim3(512), 0, stream>>>(x, wq, bq, wk, bk, wv, bv, Qb, Kb, Vb);
    attn_kernel<<<dim3(128 << lg2S), dim3(256), 0, stream>>>(Qb, Kb, Vb, (float*)d_out,
                                                             parts, statM, statL, lg2S);
    if (lg2S > 0)
        merge_kernel<<<dim3(NB * 64), dim3(256), 0, stream>>>(parts, statM, statL, (float*)d_out);
}

// Round 14
// 81.684 us; speedup vs baseline: 1.1487x; 1.1487x over previous
//
#include <hip/hip_runtime.h>

typedef _Float16 half8 __attribute__((ext_vector_type(8)));
typedef __fp16 fp16x2 __attribute__((ext_vector_type(2)));
typedef float f32x4 __attribute__((ext_vector_type(4)));
typedef float f32x16 __attribute__((ext_vector_type(16)));
typedef unsigned int u32;
typedef unsigned short u16;

#define NB 4
#define NC 128
#define NN 4096
#define THR 8.0f

__device__ __forceinline__ float h2f_u(u32 u) {
    u16 us = (u16)u;
    _Float16 h;
    __builtin_memcpy(&h, &us, 2);
    return (float)h;
}
__device__ __forceinline__ u16 f2h_u(float f) {
    _Float16 h = (_Float16)f;
    u16 us;
    __builtin_memcpy(&us, &h, 2);
    return us;
}
__device__ __forceinline__ float exp2_fast(float x) {
#if __has_builtin(__builtin_amdgcn_exp2f)
    return __builtin_amdgcn_exp2f(x);
#else
    return exp2f(x);
#endif
}
__device__ __forceinline__ int xs_addr(int c, int n) {
    return ((c << 8) + (n << 2)) ^ (((c >> 3) & 1) << 6);
}

// ---------------------------------------------------------------------------
// Kernel 1: QKV projection via fp16 MFMA. Outputs in FRAGMENT-MAJOR layout:
//  Qf[b]: per 32-q group g (8KB): chunk kc (1KB) : lane*16B
//         content = Q[g*32 + (lane&31)][kc*16 + (lane>>5)*8 .. +8)
//  Kf[b]: per 64-kv tile t (16KB): chunk (kc*2+ct) : lane*16B
//         content = K[t*64 + ct*32 + P(lane&31)][kc*16 + (lane>>5)*8 .. +8)
//         P swaps bits 2,3 (aligns QK^T D-rows with PV A-frag slots)
//  Vf[b]: per 64-kv tile t (16KB): chunk (ks*4+ct) : lane*16B
//         content = V[chan c = ct*32 + (lane&31)][t*64 + ks*16 + (lane>>5)*8 ..)
// Attn then loads every MFMA A-fragment as ONE coalesced dwordx4 from L1/L2.
// ---------------------------------------------------------------------------
__global__ __launch_bounds__(512, 2) void qkv_proj_kernel(
    const float* __restrict__ x,
    const float* __restrict__ wq, const float* __restrict__ bq,
    const float* __restrict__ wk, const float* __restrict__ bk,
    const float* __restrict__ wv, const float* __restrict__ bv,
    _Float16* __restrict__ Qf, _Float16* __restrict__ Kf, _Float16* __restrict__ Vf)
{
    const int tid  = threadIdx.x;
    const int b    = blockIdx.x >> 6;
    const int n0   = (blockIdx.x & 63) << 6;
    const int lane = tid & 63;
    const int wave = __builtin_amdgcn_readfirstlane(tid >> 6);
    const int l15  = lane & 15, lg = lane >> 4;
    const int obase = wave * 16;
    const size_t TEH = (size_t)NN * NC;

    __shared__ __align__(16) unsigned char xsm[32768];

    #pragma unroll
    for (int kk = 0; kk < 4; ++kk) {
        int g = kk * 512 + tid;
        int c = g >> 4, n4 = (g & 15) << 2;
        *(float4*)(xsm + xs_addr(c, n4)) = *(const float4*)(x + (size_t)(b * NC + c) * NN + n0 + n4);
    }
    __syncthreads();

    half8 bx[4][4];
    #pragma unroll
    for (int ct2 = 0; ct2 < 4; ++ct2) {
        int n = ct2 * 16 + l15;
        #pragma unroll
        for (int kc = 0; kc < 4; ++kc) {
            half8 h;
            #pragma unroll
            for (int j = 0; j < 8; ++j) {
                int c = kc * 32 + lg * 8 + j;
                h[j] = (_Float16)(*(const float*)(xsm + xs_addr(c, n)));
            }
            bx[ct2][kc] = h;
        }
    }
    __syncthreads();                       // xsm free for output bounce

    #pragma unroll 1
    for (int mat = 0; mat < 3; ++mat) {
        const float* __restrict__ W  = (mat == 0) ? wq : ((mat == 1) ? wk : wv);
        const float* __restrict__ bi = (mat == 0) ? bq : ((mat == 1) ? bk : bv);

        half8 aw[4];
        #pragma unroll
        for (int kc = 0; kc < 4; ++kc) {
            const float* wp = W + (size_t)(obase + l15) * NC + kc * 32 + lg * 8;
            float4 w0 = *(const float4*)(wp);
            float4 w1 = *(const float4*)(wp + 4);
            half8 h;
            h[0] = (_Float16)w0.x; h[1] = (_Float16)w0.y; h[2] = (_Float16)w0.z; h[3] = (_Float16)w0.w;
            h[4] = (_Float16)w1.x; h[5] = (_Float16)w1.y; h[6] = (_Float16)w1.z; h[7] = (_Float16)w1.w;
            aw[kc] = h;
        }
        float bvv[4];
        #pragma unroll
        for (int r = 0; r < 4; ++r) bvv[r] = bi[obase + lg * 4 + r];

        f32x4 acc[4];
        #pragma unroll
        for (int ct2 = 0; ct2 < 4; ++ct2) acc[ct2] = (f32x4){0.f, 0.f, 0.f, 0.f};
        #pragma unroll
        for (int kc = 0; kc < 4; ++kc) {
            #pragma unroll
            for (int ct2 = 0; ct2 < 4; ++ct2)
                acc[ct2] = __builtin_amdgcn_mfma_f32_16x16x32_f16(aw[kc], bx[ct2][kc], acc[ct2], 0, 0, 0);
        }

        if (mat < 2) {
            // bounce through LDS: tile [64 n][128 c] fp16, swizzled 16B slots
            const int cslot = wave * 2 + (lg >> 1);
            const int half8off = (lg & 1) * 8;
            #pragma unroll
            for (int ct2 = 0; ct2 < 4; ++ct2) {
                int nl = ct2 * 16 + l15;
                u16 pk[4];
                #pragma unroll
                for (int r = 0; r < 4; ++r) pk[r] = f2h_u(acc[ct2][r] + bvv[r]);
                unsigned long long v;
                __builtin_memcpy(&v, pk, 8);
                *(unsigned long long*)(xsm + nl * 256 + (((cslot ^ (nl & 15)) << 4) | half8off)) = v;
            }
            __syncthreads();
            if (mat == 0) {
                #pragma unroll
                for (int hf = 0; hf < 2; ++hf) {
                    int off = tid * 32 + hf * 16;          // byte offset in 16KB tile
                    int gg  = off >> 13;                   // 32-q group within tile
                    int kc  = (off >> 10) & 7;
                    int ln  = (off & 1023) >> 4;
                    int l31v = ln & 31, hiv = ln >> 5;
                    int nl  = gg * 32 + l31v;
                    int c16 = kc * 2 + hiv;
                    uint4 v = *(const uint4*)(xsm + nl * 256 + ((c16 ^ (nl & 15)) << 4));
                    *(uint4*)(Qf + (size_t)b * TEH + (size_t)((n0 >> 5) + gg) * 4096 + kc * 512 + ln * 8) = v;
                }
            } else {
                #pragma unroll
                for (int hf = 0; hf < 2; ++hf) {
                    int off = tid * 32 + hf * 16;
                    int chunk = off >> 10;                 // kc*2+ct
                    int ct  = chunk & 1;
                    int ln  = (off & 1023) >> 4;
                    int l31v = ln & 31, hiv = ln >> 5;
                    int pl  = (l31v & 19) | ((l31v & 4) << 1) | ((l31v & 8) >> 1);  // swap bits 2,3
                    int nl  = ct * 32 + pl;
                    int c16 = (chunk >> 1) * 2 + hiv;
                    uint4 v = *(const uint4*)(xsm + nl * 256 + ((c16 ^ (nl & 15)) << 4));
                    *(uint4*)(Kf + (size_t)b * TEH + (size_t)(n0 >> 6) * 8192 + chunk * 512 + ln * 8) = v;
                }
            }
            __syncthreads();
        } else {
            _Float16* vbase = Vf + (size_t)b * TEH + (size_t)(n0 >> 6) * 8192;
            #pragma unroll
            for (int ct2 = 0; ct2 < 4; ++ct2) {
                int nlcl = ct2 * 16 + l15;     // ks = ct2
                int hiv = (nlcl >> 3) & 1, j = nlcl & 7;
                #pragma unroll
                for (int r = 0; r < 4; ++r) {
                    int c = obase + lg * 4 + r;
                    int ctv = c >> 5, l31v = c & 31;
                    vbase[(ct2 * 4 + ctv) * 512 + (hiv * 32 + l31v) * 8 + j] =
                        (_Float16)(acc[ct2][r] + bvv[r]);
                }
            }
        }
    }
}

// ---------------------------------------------------------------------------
// Kernel 2: flash attention, LDS-FREE main loop. All MFMA A-fragments loaded
// as coalesced dwordx4 from fragment-major Qf/Kf/Vf (L1/L2-resident; the 4
// waves of a block read identical K/V chunks -> L1 broadcast). No barriers:
// waves fully independent. fr[16] time-shares K(it) / V(it) / K(it+1):
// V loads issue before softmax (latency hidden), K(it+1) after PV.
// 32x32x16 MFMA, 32 q/wave, kv-split S=4. VGPR ~230 -> 2 waves/SIMD.
// ---------------------------------------------------------------------------
__global__ __launch_bounds__(256, 1) void attn_kernel(
    const _Float16* __restrict__ Qf, const _Float16* __restrict__ Kf,
    const _Float16* __restrict__ Vf, float* __restrict__ out,
    u16* __restrict__ parts, float* __restrict__ statM, float* __restrict__ statL,
    int lg2S)
{
    const int S = 1 << lg2S;
    const int tid = threadIdx.x;
    const int cpx = gridDim.x >> 3;
    const int lin = (blockIdx.x & 7) * cpx + (blockIdx.x >> 3);
    const int qt   = lin & 31;             // 32 q-tiles of 128
    const int rest = lin >> 5;             // = b * S + sp
    const int sp = rest & (S - 1);
    const int b  = rest >> lg2S;

    const int n0    = qt << 7;             // 128 q per block
    const int kvlen = NN >> lg2S;
    const int kv0   = sp * kvlen;
    const int iters = kvlen >> 6;

    const int lane = tid & 63;
    const int wave = __builtin_amdgcn_readfirstlane(tid >> 6);
    const int l31 = lane & 31, hi = lane >> 5;

    const size_t TEH = (size_t)NN * NC;
    const _Float16* qb = Qf + (size_t)b * TEH + (size_t)((n0 >> 5) + wave) * 4096 + lane * 8;
    const _Float16* kb = Kf + (size_t)b * TEH + (size_t)(kv0 >> 6) * 8192 + lane * 8;
    const _Float16* vb = Vf + (size_t)b * TEH + (size_t)(kv0 >> 6) * 8192 + lane * 8;

    // ---- Q fragments (B operand), loaded once ----
    half8 aq[8];
    #pragma unroll
    for (int kc = 0; kc < 8; ++kc) aq[kc] = *(const half8*)(qb + kc * 512);

    // ---- fr: shared K/V fragment registers; prologue loads K(0) ----
    half8 fr[16];
    #pragma unroll
    for (int i = 0; i < 16; ++i) fr[i] = *(const half8*)(kb + i * 512);

    float mrun = -3.0e38f, lsum = 0.f;
    f32x16 o[4];
    #pragma unroll
    for (int ct = 0; ct < 4; ++ct)
        #pragma unroll
        for (int r = 0; r < 16; ++r) o[ct][r] = 0.f;

    const float L2E = 1.44269504f;

    for (int it = 0; it < iters; ++it) {
        // ---- S = K Q^T : D[perm kv slot][q=l31] ----
        f32x16 s0, s1;
        #pragma unroll
        for (int r = 0; r < 16; ++r) { s0[r] = 0.f; s1[r] = 0.f; }
        __builtin_amdgcn_s_setprio(1);
        #pragma unroll
        for (int kc = 0; kc < 8; ++kc) {
            s0 = __builtin_amdgcn_mfma_f32_32x32x16_f16(fr[kc * 2],     aq[kc], s0, 0, 0, 0);
            s1 = __builtin_amdgcn_mfma_f32_32x32x16_f16(fr[kc * 2 + 1], aq[kc], s1, 0, 0, 0);
        }
        __builtin_amdgcn_s_setprio(0);

        // ---- issue V(it) loads (land under softmax) ----
        {
            const _Float16* vt = vb + (size_t)it * 8192;
            #pragma unroll
            for (int i = 0; i < 16; ++i) fr[i] = *(const half8*)(vt + i * 512);
        }

        // ---- online softmax, in-lane for q = l31; defer-rescale THR ----
        float tm = fmaxf(s0[0], s0[1]);
        #pragma unroll
        for (int r = 2; r < 16; r += 2) tm = fmaxf(tm, fmaxf(s0[r], s0[r + 1]));
        #pragma unroll
        for (int r = 0; r < 16; r += 2) tm = fmaxf(tm, fmaxf(s1[r], s1[r + 1]));
        tm = fmaxf(tm, __shfl_xor(tm, 32, 64));

        if (__any(tm > mrun + THR)) {
            float mnew = fmaxf(mrun, tm);
            float sc = __expf(mrun - mnew);    // first iter: exp(-inf) = 0
            #pragma unroll
            for (int ct = 0; ct < 4; ++ct)
                #pragma unroll
                for (int r = 0; r < 16; ++r) o[ct][r] *= sc;
            lsum *= sc;
            mrun = mnew;
        }
        float nm = -mrun * L2E;
        float psum = 0.f;
        #pragma unroll
        for (int r = 0; r < 16; ++r) {
            s0[r] = exp2_fast(fmaf(s0[r], L2E, nm));
            s1[r] = exp2_fast(fmaf(s1[r], L2E, nm));
            psum += s0[r] + s1[r];
        }
        psum += __shfl_xor(psum, 32, 64);
        lsum += psum;

        // ---- P -> A-frags, fully in-lane ----
        union H8 { fp16x2 h2[4]; half8 h8; };
        half8 pa[4];
        {
            H8 u0, u1, u2, u3;
            #pragma unroll
            for (int t = 0; t < 4; ++t) {
                u0.h2[t] = __builtin_amdgcn_cvt_pkrtz(s0[2 * t],     s0[2 * t + 1]);
                u1.h2[t] = __builtin_amdgcn_cvt_pkrtz(s0[8 + 2 * t], s0[9 + 2 * t]);
                u2.h2[t] = __builtin_amdgcn_cvt_pkrtz(s1[2 * t],     s1[2 * t + 1]);
                u3.h2[t] = __builtin_amdgcn_cvt_pkrtz(s1[8 + 2 * t], s1[9 + 2 * t]);
            }
            pa[0] = u0.h8; pa[1] = u1.h8; pa[2] = u2.h8; pa[3] = u3.h8;
        }

        // ---- O += V^T P : D[c][q=l31] ----
        __builtin_amdgcn_s_setprio(1);
        #pragma unroll
        for (int ks = 0; ks < 4; ++ks) {
            #pragma unroll
            for (int ct = 0; ct < 4; ++ct)
                o[ct] = __builtin_amdgcn_mfma_f32_32x32x16_f16(fr[ks * 4 + ct], pa[ks], o[ct], 0, 0, 0);
        }
        __builtin_amdgcn_s_setprio(0);

        // ---- issue K(it+1) loads (land by next QK) ----
        if (it + 1 < iters) {
            const _Float16* kt = kb + (size_t)(it + 1) * 8192;
            #pragma unroll
            for (int i = 0; i < 16; ++i) fr[i] = *(const half8*)(kt + i * 512);
        }
    }

    // ---- epilogue (all q-column-local); partials normalized per split ----
    const int nq = n0 + wave * 32 + l31;
    const int rbase = 4 * hi;
    float inv = 1.0f / lsum;
    if (lg2S == 0) {
        #pragma unroll
        for (int ct = 0; ct < 4; ++ct)
            #pragma unroll
            for (int rg = 0; rg < 16; ++rg) {
                int c = ct * 32 + (rg & 3) + ((rg >> 2) << 3) + rbase;
                out[(size_t)(b * NC + c) * NN + nq] = o[ct][rg] * inv;
            }
    } else {
        if (hi == 0) {
            statM[(sp * NB + b) * NN + nq] = mrun;
            statL[(sp * NB + b) * NN + nq] = lsum;
        }
        const size_t pbase = (size_t)sp * ((size_t)NB * NC * NN) + (size_t)b * NC * NN + nq;
        #pragma unroll
        for (int ct = 0; ct < 4; ++ct)
            #pragma unroll
            for (int rg = 0; rg < 16; ++rg) {
                int c = ct * 32 + (rg & 3) + ((rg >> 2) << 3) + rbase;
                parts[pbase + (size_t)c * NN] = f2h_u(o[ct][rg] * inv);
            }
    }
}

// ---------------------------------------------------------------------------
// Kernel 3: merge 4 normalized partials. grid NB*64, block 256.
// ---------------------------------------------------------------------------
__global__ __launch_bounds__(256) void merge_kernel(
    const u16* __restrict__ parts,
    const float* __restrict__ statM, const float* __restrict__ statL,
    float* __restrict__ out)
{
    const int b  = blockIdx.x >> 6;
    const int nb = (blockIdx.x & 63) << 6;
    const int t  = threadIdx.x;
    const int n  = nb + ((t & 31) << 1);
    const int cg = t >> 5;
    const size_t PST = (size_t)NB * NC * NN;

    float w0[4], w1[4];
    {
        float M0 = -3.0e38f, M1 = -3.0e38f;
        #pragma unroll
        for (int sp = 0; sp < 4; ++sp) {
            w0[sp] = statM[(sp * NB + b) * NN + n];
            w1[sp] = statM[(sp * NB + b) * NN + n + 1];
            M0 = fmaxf(M0, w0[sp]); M1 = fmaxf(M1, w1[sp]);
        }
        float d0 = 0.f, d1 = 0.f;
        #pragma unroll
        for (int sp = 0; sp < 4; ++sp) {
            float e0 = __expf(w0[sp] - M0) * statL[(sp * NB + b) * NN + n];
            float e1 = __expf(w1[sp] - M1) * statL[(sp * NB + b) * NN + n + 1];
            w0[sp] = e0; w1[sp] = e1; d0 += e0; d1 += e1;
        }
        d0 = 1.f / d0; d1 = 1.f / d1;
        #pragma unroll
        for (int sp = 0; sp < 4; ++sp) { w0[sp] *= d0; w1[sp] *= d1; }
    }

    #pragma unroll 4
    for (int i = 0; i < 16; ++i) {
        int c = cg * 16 + i;
        size_t e = (size_t)(b * NC + c) * NN + n;
        float a0 = 0.f, a1 = 0.f;
        #pragma unroll
        for (int sp = 0; sp < 4; ++sp) {
            u32 v = *(const u32*)(parts + sp * PST + e);
            a0 += w0[sp] * h2f_u(v);
            a1 += w1[sp] * h2f_u(v >> 16);
        }
        float2 r; r.x = a0; r.y = a1;
        *(float2*)(out + e) = r;
    }
}

extern "C" void kernel_launch(void* const* d_in, const int* in_sizes, int n_in,
                              void* d_out, int out_size, void* d_ws, size_t ws_size,
                              hipStream_t stream)
{
    const float* x  = (const float*)d_in[0];
    const float* wq = (const float*)d_in[1];
    const float* bq = (const float*)d_in[2];
    const float* wk = (const float*)d_in[3];
    const float* bk = (const float*)d_in[4];
    const float* wv = (const float*)d_in[5];
    const float* bv = (const float*)d_in[6];

    const size_t TE = (size_t)NB * NN * NC;              // 2M elems / tensor
    _Float16* Qf = (_Float16*)d_ws;
    _Float16* Kf = Qf + TE;
    _Float16* Vf = Kf + TE;
    char* base = (char*)d_ws;
    const size_t statOff = 3 * TE * 2;                   // 12 MB
    const size_t statSz  = (size_t)4 * NB * NN * 4;      // 256 KB (S=4)
    float* statM = (float*)(base + statOff);
    float* statL = (float*)(base + statOff + statSz);
    const size_t pOff = statOff + 2 * statSz;
    u16* parts = (u16*)(base + pOff);
    const size_t need = pOff + 4 * TE * 2;               // + 16 MB partials

    int lg2S = (ws_size >= need) ? 2 : 0;                // S=4 or fallback S=1

    qkv_proj_kernel<<<dim3(256), dim3(512), 0, stream>>>(x, wq, bq, wk, bk, wv, bv, Qf, Kf, Vf);
    attn_kernel<<<dim3(128 << lg2S), dim3(256), 0, stream>>>(Qf, Kf, Vf, (float*)d_out,
                                                             parts, statM, statL, lg2S);
    if (lg2S > 0)
        merge_kernel<<<dim3(NB * 64), dim3(256), 0, stream>>>(parts, statM, statL, (float*)d_out);
}